// Round 4
// baseline (987.174 us; speedup 1.0000x reference)
//
#include <hip/hip_runtime.h>
#include <cstddef>
#include <cstdint>

#define D_MODEL 256
#define LQ 19950
#define NBATCH 2
#define NT (NBATCH*LQ)

typedef short  bf16x8 __attribute__((ext_vector_type(8)));
typedef float  f32x4  __attribute__((ext_vector_type(4)));
typedef unsigned short u16x8 __attribute__((ext_vector_type(8)));

__device__ __forceinline__ unsigned short f2b(float f) {
  unsigned u = __float_as_uint(f);
  u += 0x7fff + ((u >> 16) & 1);          // RNE
  return (unsigned short)(u >> 16);
}
__device__ __forceinline__ float b2f(unsigned short s) {
  return __uint_as_float(((unsigned)s) << 16);
}
__device__ __forceinline__ bf16x8 pack8(float4 a, float4 b) {
  bf16x8 r;
  r[0]=(short)f2b(a.x); r[1]=(short)f2b(a.y); r[2]=(short)f2b(a.z); r[3]=(short)f2b(a.w);
  r[4]=(short)f2b(b.x); r[5]=(short)f2b(b.y); r[6]=(short)f2b(b.z); r[7]=(short)f2b(b.w);
  return r;
}

__device__ __forceinline__ void tok_level(int tok, int& H, int& W, int& loff, int& lvl) {
  if (tok < 15200)      { lvl=0; H=100; W=152; loff=0; }
  else if (tok < 19000) { lvl=1; H=50;  W=76;  loff=15200; }
  else                  { lvl=2; H=25;  W=38;  loff=19000; }
}

// ================= 64x64 bf16-MFMA GEMM (small-N / BKN cases) =================
template<bool ABF, bool BKN, bool CBF, bool RELU, bool ROWBIAS>
__global__ __launch_bounds__(256) void mgemm(
    const void* __restrict__ Av, const float* __restrict__ Bv,
    const float* __restrict__ bias, void* __restrict__ Cv,
    int M, int N, int K, int lda, int ldb, long sB, long sC)
{
  __shared__ unsigned short As[64][72];
  __shared__ unsigned short Bs[64][72];
  const int tid = threadIdx.x;
  const float* Bp = Bv + (size_t)blockIdx.z * sB;
  const int n0 = blockIdx.x * 64, m0 = blockIdx.y * 64;
  const int lane = tid & 63;
  const int wave = tid >> 6;
  const int l15 = lane & 15, q = lane >> 4;
  const int m_off = (wave >> 1) * 32, n_off = (wave & 1) * 32;
  f32x4 acc[2][2] = {};

  for (int k0 = 0; k0 < K; k0 += 64) {
    {
      int row = tid >> 2, kc = (tid & 3) * 8;
      int gm = m0 + row;
      bf16x8 v0 = (bf16x8)0, v1 = (bf16x8)0;
      if (gm < M) {
        if constexpr (ABF) {
          const unsigned short* A = (const unsigned short*)Av;
          v0 = *(const bf16x8*)&A[(size_t)gm*lda + k0 + kc];
          v1 = *(const bf16x8*)&A[(size_t)gm*lda + k0 + kc + 32];
        } else {
          const float* A = (const float*)Av;
          const float* p = &A[(size_t)gm*lda + k0 + kc];
          v0 = pack8(*(const float4*)p,      *(const float4*)(p+4));
          v1 = pack8(*(const float4*)(p+32), *(const float4*)(p+36));
        }
      }
      *(bf16x8*)&As[row][kc]    = v0;
      *(bf16x8*)&As[row][kc+32] = v1;
    }
    if constexpr (!BKN) {
      int row = tid >> 2, kc = (tid & 3) * 8;
      int gn = n0 + row;
      bf16x8 v0 = (bf16x8)0, v1 = (bf16x8)0;
      if (gn < N) {
        const float* p = &Bp[(size_t)gn*ldb + k0 + kc];
        v0 = pack8(*(const float4*)p,      *(const float4*)(p+4));
        v1 = pack8(*(const float4*)(p+32), *(const float4*)(p+36));
      }
      *(bf16x8*)&Bs[row][kc]    = v0;
      *(bf16x8*)&Bs[row][kc+32] = v1;
    } else {
      int kr = tid >> 3, nc = (tid & 7) * 8;
      #pragma unroll
      for (int half = 0; half < 2; ++half) {
        int kk = kr + half*32;
        const float* p = &Bp[(size_t)(k0+kk)*ldb + n0 + nc];
        float v[8];
        if (n0 + nc + 7 < N) {
          float2 a0 = *(const float2*)p,     a1 = *(const float2*)(p+2);
          float2 a2 = *(const float2*)(p+4), a3 = *(const float2*)(p+6);
          v[0]=a0.x; v[1]=a0.y; v[2]=a1.x; v[3]=a1.y;
          v[4]=a2.x; v[5]=a2.y; v[6]=a3.x; v[7]=a3.y;
        } else {
          #pragma unroll
          for (int i=0;i<8;++i) v[i] = (n0+nc+i < N) ? p[i] : 0.f;
        }
        #pragma unroll
        for (int i=0;i<8;++i) Bs[nc+i][kk] = f2b(v[i]);
      }
    }
    __syncthreads();
    #pragma unroll
    for (int s = 0; s < 2; ++s) {
      bf16x8 a0 = *(const bf16x8*)&As[m_off      + l15][s*32 + q*8];
      bf16x8 a1 = *(const bf16x8*)&As[m_off + 16 + l15][s*32 + q*8];
      bf16x8 b0 = *(const bf16x8*)&Bs[n_off      + l15][s*32 + q*8];
      bf16x8 b1 = *(const bf16x8*)&Bs[n_off + 16 + l15][s*32 + q*8];
      acc[0][0] = __builtin_amdgcn_mfma_f32_16x16x32_bf16(a0, b0, acc[0][0], 0,0,0);
      acc[0][1] = __builtin_amdgcn_mfma_f32_16x16x32_bf16(a0, b1, acc[0][1], 0,0,0);
      acc[1][0] = __builtin_amdgcn_mfma_f32_16x16x32_bf16(a1, b0, acc[1][0], 0,0,0);
      acc[1][1] = __builtin_amdgcn_mfma_f32_16x16x32_bf16(a1, b1, acc[1][1], 0,0,0);
    }
    __syncthreads();
  }
  float* Cf = (float*)Cv + (size_t)blockIdx.z * sC;
  unsigned short* Cb = (unsigned short*)Cv + (size_t)blockIdx.z * sC;
  #pragma unroll
  for (int r = 0; r < 2; ++r) {
    #pragma unroll
    for (int c = 0; c < 2; ++c) {
      #pragma unroll
      for (int v = 0; v < 4; ++v) {
        int gm = m0 + m_off + r*16 + q*4 + v;
        int gn = n0 + n_off + c*16 + l15;
        if (gm < M && gn < N) {
          float o = acc[r][c][v];
          if (bias) o += ROWBIAS ? bias[gm] : bias[gn];
          if (RELU) o = fmaxf(o, 0.f);
          if constexpr (CBF) Cb[(size_t)gm*N + gn] = f2b(o);
          else               Cf[(size_t)gm*N + gn] = o;
        }
      }
    }
  }
}

// ================= 128x128 bf16-MFMA GEMM (B[N,K] weights) =================
// 4 waves, each computes 64x64 via 4x4 frags of mfma_f32_16x16x32_bf16.
template<bool ABF, bool CBF, bool RELU>
__global__ __launch_bounds__(256) void mgemm128(
    const void* __restrict__ Av, const float* __restrict__ Bv,
    const float* __restrict__ bias, void* __restrict__ Cv,
    int M, int N, int K, int lda, int ldb)
{
  __shared__ unsigned short As[128][72];
  __shared__ unsigned short Bs[128][72];
  const int tid = threadIdx.x;
  const int n0 = blockIdx.x * 128, m0 = blockIdx.y * 128;
  const int lane = tid & 63, wave = tid >> 6;
  const int l15 = lane & 15, q = lane >> 4;
  const int m_off = (wave >> 1) * 64, n_off = (wave & 1) * 64;
  f32x4 acc[4][4] = {};

  const int row = tid >> 1, kc = (tid & 1) * 32;
  for (int k0 = 0; k0 < K; k0 += 64) {
    // ---- stage A rows (row, k0+kc .. +31) ----
    {
      int gm = m0 + row;
      bf16x8 v0=(bf16x8)0, v1=(bf16x8)0, v2=(bf16x8)0, v3=(bf16x8)0;
      if (gm < M) {
        if constexpr (ABF) {
          const unsigned short* A = (const unsigned short*)Av;
          const unsigned short* p = &A[(size_t)gm*lda + k0 + kc];
          v0 = *(const bf16x8*)p;      v1 = *(const bf16x8*)(p+8);
          v2 = *(const bf16x8*)(p+16); v3 = *(const bf16x8*)(p+24);
        } else {
          const float* A = (const float*)Av;
          const float* p = &A[(size_t)gm*lda + k0 + kc];
          v0 = pack8(*(const float4*)p,      *(const float4*)(p+4));
          v1 = pack8(*(const float4*)(p+8),  *(const float4*)(p+12));
          v2 = pack8(*(const float4*)(p+16), *(const float4*)(p+20));
          v3 = pack8(*(const float4*)(p+24), *(const float4*)(p+28));
        }
      }
      *(bf16x8*)&As[row][kc]    = v0;
      *(bf16x8*)&As[row][kc+8]  = v1;
      *(bf16x8*)&As[row][kc+16] = v2;
      *(bf16x8*)&As[row][kc+24] = v3;
    }
    // ---- stage B rows (gn, k) from B[N,K] fp32 ----
    {
      int gn = n0 + row;
      bf16x8 v0=(bf16x8)0, v1=(bf16x8)0, v2=(bf16x8)0, v3=(bf16x8)0;
      if (gn < N) {
        const float* p = &Bv[(size_t)gn*ldb + k0 + kc];
        v0 = pack8(*(const float4*)p,      *(const float4*)(p+4));
        v1 = pack8(*(const float4*)(p+8),  *(const float4*)(p+12));
        v2 = pack8(*(const float4*)(p+16), *(const float4*)(p+20));
        v3 = pack8(*(const float4*)(p+24), *(const float4*)(p+28));
      }
      *(bf16x8*)&Bs[row][kc]    = v0;
      *(bf16x8*)&Bs[row][kc+8]  = v1;
      *(bf16x8*)&Bs[row][kc+16] = v2;
      *(bf16x8*)&Bs[row][kc+24] = v3;
    }
    __syncthreads();
    #pragma unroll
    for (int s = 0; s < 2; ++s) {
      bf16x8 af[4], bfr[4];
      #pragma unroll
      for (int i = 0; i < 4; ++i)
        af[i] = *(const bf16x8*)&As[m_off + i*16 + l15][s*32 + q*8];
      #pragma unroll
      for (int j = 0; j < 4; ++j)
        bfr[j] = *(const bf16x8*)&Bs[n_off + j*16 + l15][s*32 + q*8];
      #pragma unroll
      for (int i = 0; i < 4; ++i)
        #pragma unroll
        for (int j = 0; j < 4; ++j)
          acc[i][j] = __builtin_amdgcn_mfma_f32_16x16x32_bf16(af[i], bfr[j], acc[i][j], 0,0,0);
    }
    __syncthreads();
  }
  float* Cf = (float*)Cv;
  unsigned short* Cb = (unsigned short*)Cv;
  #pragma unroll
  for (int i = 0; i < 4; ++i) {
    #pragma unroll
    for (int j = 0; j < 4; ++j) {
      #pragma unroll
      for (int v = 0; v < 4; ++v) {
        int gm = m0 + m_off + i*16 + q*4 + v;
        int gn = n0 + n_off + j*16 + l15;
        if (gm < M && gn < N) {
          float o = acc[i][j][v];
          if (bias) o += bias[gn];
          if (RELU) o = fmaxf(o, 0.f);
          if constexpr (CBF) Cb[(size_t)gm*N + gn] = f2b(o);
          else               Cf[(size_t)gm*N + gn] = o;
        }
      }
    }
  }
}

// ---------- GN stage 1: partial sums, grid (32 groups, N, 8 chunks) ----------
__global__ __launch_bounds__(256) void gn_partial(
    const float* __restrict__ s, float* __restrict__ partials, int HW)
{
  int g = blockIdx.x, n = blockIdx.y, c = blockIdx.z;
  const float4* base = (const float4*)(s + ((size_t)n*D_MODEL + g*8) * HW);
  int nvec = (8*HW) >> 2;
  float sum = 0.f, sq = 0.f;
  for (int j = c*256 + threadIdx.x; j < nvec; j += 2048) {
    float4 v = base[j];
    sum += v.x+v.y+v.z+v.w;
    sq  += v.x*v.x+v.y*v.y+v.z*v.z+v.w*v.w;
  }
  #pragma unroll
  for (int m=32;m;m>>=1){ sum += __shfl_xor(sum,m,64); sq += __shfl_xor(sq,m,64); }
  __shared__ float s1[4], s2[4];
  int w = threadIdx.x >> 6;
  if ((threadIdx.x & 63) == 0) { s1[w]=sum; s2[w]=sq; }
  __syncthreads();
  if (threadIdx.x == 0) {
    partials[(((size_t)n*32+g)*8 + c)*2]     = s1[0]+s1[1]+s1[2]+s1[3];
    partials[(((size_t)n*32+g)*8 + c)*2 + 1] = s2[0]+s2[1]+s2[2]+s2[3];
  }
}

__global__ __launch_bounds__(64) void gn_finalize(
    const float* __restrict__ partials, float* __restrict__ stats, int HW)
{
  int t = threadIdx.x;
  float S = 0.f, Q = 0.f;
  #pragma unroll
  for (int c = 0; c < 8; ++c) {
    S += partials[((size_t)t*8 + c)*2];
    Q += partials[((size_t)t*8 + c)*2 + 1];
  }
  float inv = 1.f/(float)(8*HW);
  float mu = S*inv;
  float var = Q*inv - mu*mu;
  stats[(size_t)t*2]   = mu;
  stats[(size_t)t*2+1] = rsqrtf(var + 1e-5f);
}

// ---------- apply GN + transpose ----------
__global__ __launch_bounds__(256) void gn_apply(
    const float* __restrict__ s, const float* __restrict__ stats,
    const float* __restrict__ gw, const float* __restrict__ gb,
    float* __restrict__ src, int HW, int loff)
{
  __shared__ float T[32][33];
  int tx = threadIdx.x & 31, ty = threadIdx.x >> 5;
  int hw0 = blockIdx.x*32, o0 = blockIdx.y*32, n = blockIdx.z;
  const float* base = s + (size_t)n*D_MODEL*HW;
  #pragma unroll
  for (int it=0; it<4; ++it) {
    int ol = ty + it*8;
    int o = o0 + ol;
    int hw = hw0 + tx;
    float v = 0.f;
    if (hw < HW) {
      int grp = o >> 3;
      float mu   = stats[((size_t)n*32+grp)*2];
      float rstd = stats[((size_t)n*32+grp)*2+1];
      v = (base[(size_t)o*HW + hw] - mu)*rstd*gw[o] + gb[o];
    }
    T[ol][tx] = v;
  }
  __syncthreads();
  #pragma unroll
  for (int it=0; it<4; ++it) {
    int tl = ty + it*8;
    int tok = hw0 + tl;
    if (tok < HW) {
      src[((size_t)n*LQ + loff + tok)*D_MODEL + o0 + tx] = T[tx][tl];
    }
  }
}

// ---------- q = bf16(src + sine_pos + level_embed), fast trig ----------
__global__ __launch_bounds__(256) void compute_q(
    const float* __restrict__ src, const float* __restrict__ level_embed,
    unsigned short* __restrict__ q)
{
  int row = blockIdx.x;
  int d = threadIdx.x;
  int tok = row % LQ;
  int H,W,loff,lvl; tok_level(tok,H,W,loff,lvl);
  int hw = tok - loff;
  int i = hw / W, j = hw % W;
  const float TWO_PI = 6.28318530717958647692f;
  float yv = (float)(i+1) / ((float)H + 1e-6f) * TWO_PI;
  float xv = (float)(j+1) / ((float)W + 1e-6f) * TWO_PI;
  int m = (d & 127) >> 1;
  // 1/t = exp(-m * ln(10000)/64)
  float invt = __expf((float)m * -0.14391156516f);
  float ang = ((d < 128) ? yv : xv) * invt;
  float pe = (d & 1) ? __cosf(ang) : __sinf(ang);
  size_t idx = (size_t)row*D_MODEL + d;
  q[idx] = f2b(src[idx] + pe + level_embed[lvl*D_MODEL + d]);
}

// ---------- deformable sampling: one thread per (row, head), 32 ch ----------
__global__ __launch_bounds__(256) void deform_sample(
    const unsigned short* __restrict__ value, const float* __restrict__ offb,
    const float* __restrict__ awb, unsigned short* __restrict__ accb)
{
  int row = blockIdx.x*256 + threadIdx.x;   // token row (64 consecutive per wave)
  int h = blockIdx.y;                        // head
  if (row >= NT) return;
  int n = (row >= LQ) ? 1 : 0;
  int tok = row - n*LQ;
  int Ht,Wt,lofft,lvlt; tok_level(tok,Ht,Wt,lofft,lvlt);
  int hw = tok - lofft;
  int ti = hw / Wt, tj = hw % Wt;
  float gxr = ((float)tj + 0.5f) / (float)Wt;
  float gyr = ((float)ti + 0.5f) / (float)Ht;

  // load 24 offsets + 12 logits (vectorized)
  const float* offr = offb + (size_t)row*192 + h*24;
  const float* awr  = awb  + (size_t)row*96  + h*12;
  float off[24];
  #pragma unroll
  for (int v4 = 0; v4 < 6; ++v4) {
    float4 o4 = *(const float4*)(offr + v4*4);
    off[v4*4]=o4.x; off[v4*4+1]=o4.y; off[v4*4+2]=o4.z; off[v4*4+3]=o4.w;
  }
  float lg[12];
  #pragma unroll
  for (int v4 = 0; v4 < 3; ++v4) {
    float4 a4 = *(const float4*)(awr + v4*4);
    lg[v4*4]=a4.x; lg[v4*4+1]=a4.y; lg[v4*4+2]=a4.z; lg[v4*4+3]=a4.w;
  }
  float mx = -1e30f;
  #pragma unroll
  for (int i=0;i<12;++i) mx = fmaxf(mx, lg[i]);
  float ssum = 0.f;
  #pragma unroll
  for (int i=0;i<12;++i){ lg[i] = __expf(lg[i]-mx); ssum += lg[i]; }
  float sinv = 1.f/ssum;

  float acc[32];
  #pragma unroll
  for (int c=0;c<32;++c) acc[c]=0.f;

  const int HH[3]={100,50,25}, WW[3]={152,76,38}, OO[3]={0,15200,19000};
  #pragma unroll
  for (int lvl=0; lvl<3; ++lvl) {
    const int H=HH[lvl], W=WW[lvl], lo=OO[lvl];
    const unsigned short* vbase = value + ((size_t)(n*LQ + lo))*D_MODEL + h*32;
    #pragma unroll
    for (int p=0; p<4; ++p) {
      float ox = off[lvl*8 + p*2];
      float oy = off[lvl*8 + p*2 + 1];
      float a  = lg[lvl*4 + p] * sinv;
      float x = (gxr + ox / (float)W) * (float)W - 0.5f;
      float y = (gyr + oy / (float)H) * (float)H - 0.5f;
      float x0f = floorf(x), y0f = floorf(y);
      float wx = x - x0f, wy = y - y0f;
      int x0 = (int)x0f, y0 = (int)y0f;
      float tw[4] = { (1.f-wx)*(1.f-wy)*a, wx*(1.f-wy)*a, (1.f-wx)*wy*a, wx*wy*a };
      #pragma unroll
      for (int t=0; t<4; ++t) {
        int xi = x0 + (t & 1), yi = y0 + (t >> 1);
        if (xi >= 0 && xi < W && yi >= 0 && yi < H) {
          const float w = tw[t];
          const unsigned short* vr = vbase + (size_t)(yi*W + xi)*D_MODEL;
          u16x8 v0 = *(const u16x8*)vr;
          u16x8 v1 = *(const u16x8*)(vr+8);
          u16x8 v2 = *(const u16x8*)(vr+16);
          u16x8 v3 = *(const u16x8*)(vr+24);
          #pragma unroll
          for (int c=0;c<8;++c) acc[c]      += w * b2f(v0[c]);
          #pragma unroll
          for (int c=0;c<8;++c) acc[8+c]    += w * b2f(v1[c]);
          #pragma unroll
          for (int c=0;c<8;++c) acc[16+c]   += w * b2f(v2[c]);
          #pragma unroll
          for (int c=0;c<8;++c) acc[24+c]   += w * b2f(v3[c]);
        }
      }
    }
  }
  unsigned short* o = accb + (size_t)row*D_MODEL + h*32;
  u16x8 ov;
  #pragma unroll
  for (int g4=0; g4<4; ++g4) {
    #pragma unroll
    for (int c=0;c<8;++c) ov[c] = f2b(acc[g4*8+c]);
    *(u16x8*)(o + g4*8) = ov;
  }
}

// ---------- out = LN(A+B)*g+b ----------
__global__ __launch_bounds__(256) void ln_add(
    const float* __restrict__ A, const float* __restrict__ B,
    const float* __restrict__ g, const float* __restrict__ b,
    float* __restrict__ out, int rows)
{
  int wid = (blockIdx.x * 256 + threadIdx.x) >> 6;
  int lane = threadIdx.x & 63;
  if (wid >= rows) return;
  size_t base = (size_t)wid * D_MODEL;
  float4 va = *(const float4*)&A[base + lane*4];
  float4 vb = *(const float4*)&B[base + lane*4];
  float v[4] = {va.x+vb.x, va.y+vb.y, va.z+vb.z, va.w+vb.w};
  float s = v[0]+v[1]+v[2]+v[3];
  #pragma unroll
  for (int m=32; m; m>>=1) s += __shfl_xor(s, m, 64);
  float mu = s * (1.f/256.f);
  float qq = 0.f;
  #pragma unroll
  for (int i=0;i<4;++i){ float d=v[i]-mu; qq += d*d; }
  #pragma unroll
  for (int m=32; m; m>>=1) qq += __shfl_xor(qq, m, 64);
  float rstd = rsqrtf(qq*(1.f/256.f) + 1e-5f);
  #pragma unroll
  for (int i=0;i<4;++i){
    int d = lane*4+i;
    out[base+d] = (v[i]-mu)*rstd*g[d] + b[d];
  }
}

// ---------- point head bilinear ----------
__global__ __launch_bounds__(256) void point_sample(
    const float* __restrict__ x2, const float* __restrict__ pc,
    float* __restrict__ pf)
{
  int pidx = blockIdx.x;
  int n = pidx / 1000;
  float px = pc[(size_t)pidx*2], py = pc[(size_t)pidx*2+1];
  float x = ((2.f*px)*152.f - 1.f)*0.5f;
  float y = ((2.f*py)*100.f - 1.f)*0.5f;
  float x0f=floorf(x), y0f=floorf(y);
  float wx=x-x0f, wy=y-y0f;
  int x0=(int)x0f, y0=(int)y0f;
  int d = threadIdx.x;
  float accv = 0.f;
  #pragma unroll
  for (int t=0;t<4;++t) {
    int xi = x0 + (t&1), yi = y0 + (t>>1);
    float w = ((t&1)?wx:(1.f-wx)) * ((t>>1)?wy:(1.f-wy));
    if (xi>=0 && xi<152 && yi>=0 && yi<100) {
      accv += w * x2[((size_t)(n*LQ + yi*152 + xi))*D_MODEL + d];
    }
  }
  pf[(size_t)pidx*D_MODEL + d] = accv;
}

__global__ void copy_gt(const int* __restrict__ gt, float* __restrict__ out, int nels)
{
  int i = blockIdx.x*256 + threadIdx.x;
  if (i < nels) out[i] = (float)gt[i];
}

extern "C" void kernel_launch(void* const* d_in, const int* in_sizes, int n_in,
                              void* d_out, int out_size, void* d_ws, size_t ws_size,
                              hipStream_t stream)
{
  const float* feat[3]  = {(const float*)d_in[0], (const float*)d_in[1], (const float*)d_in[2]};
  const float* pc       = (const float*)d_in[3];
  const int*   gt       = (const int*)d_in[4];
  const float* projw[3] = {(const float*)d_in[5],  (const float*)d_in[9],  (const float*)d_in[13]};
  const float* projb[3] = {(const float*)d_in[6],  (const float*)d_in[10], (const float*)d_in[14]};
  const float* gng[3]   = {(const float*)d_in[7],  (const float*)d_in[11], (const float*)d_in[15]};
  const float* gnb[3]   = {(const float*)d_in[8],  (const float*)d_in[12], (const float*)d_in[16]};
  const float* level_embed = (const float*)d_in[17];
  const float* w_off  = (const float*)d_in[18];
  const float* b_off  = (const float*)d_in[19];
  const float* w_attn = (const float*)d_in[20];
  const float* b_attn = (const float*)d_in[21];
  const float* w_val  = (const float*)d_in[22];
  const float* b_val  = (const float*)d_in[23];
  const float* w_out  = (const float*)d_in[24];
  const float* b_out  = (const float*)d_in[25];
  const float* ln1g   = (const float*)d_in[26];
  const float* ln1b   = (const float*)d_in[27];
  const float* ln2g   = (const float*)d_in[28];
  const float* ln2b   = (const float*)d_in[29];
  const float* wff1   = (const float*)d_in[30];
  const float* bff1   = (const float*)d_in[31];
  const float* wff2   = (const float*)d_in[32];
  const float* bff2   = (const float*)d_in[33];
  const float* fcw    = (const float*)d_in[34];
  const float* fcb    = (const float*)d_in[35];

  // ---- workspace layout (float units) ----
  float* ws    = (float*)d_ws;
  float* s_tmp = ws;                         // 10,214,400
  float* srcb  = s_tmp + 10214400;           // 10,214,400
  float* offaw = srcb  + 10214400;           // 11,491,200
  unsigned short* value_b = (unsigned short*)(offaw + 11491200); // 10,214,400 bf16
  unsigned short* acc_b   = value_b + 10214400;                  // 10,214,400 bf16
  unsigned short* q_b     = acc_b   + 10214400;                  // 10,214,400 bf16
  float* stats    = (float*)(q_b + 10214400);   // 128
  float* partials = stats + 128;                // 1024
  float* offbuf = offaw;
  float* awbuf  = offaw + 7660800;
  float* xbuf   = offaw;
  float* pf     = (float*)acc_b;

  const int HWs[3]  = {15200, 3800, 950};
  const int Cins[3] = {512, 1024, 2048};
  const int LOFF[3] = {0, 15200, 19000};

  // 1) per-level projection (bf16 MFMA) + GN + transpose
  for (int l = 0; l < 3; ++l) {
    int HW = HWs[l], K = Cins[l];
    mgemm<false,true,false,false,true><<<dim3((HW+63)/64, 4, NBATCH), 256, 0, stream>>>(
        projw[l], feat[l], projb[l], s_tmp, D_MODEL, HW, K, K, HW,
        (long)K*HW, (long)D_MODEL*HW);
    gn_partial<<<dim3(32, NBATCH, 8), 256, 0, stream>>>(s_tmp, partials, HW);
    gn_finalize<<<1, 64, 0, stream>>>(partials, stats, HW);
    gn_apply<<<dim3((HW+31)/32, 8, NBATCH), 256, 0, stream>>>(
        s_tmp, stats, gng[l], gnb[l], srcb, HW, LOFF[l]);
  }

  // 2) q = bf16(src + pos)
  compute_q<<<NT, 256, 0, stream>>>(srcb, level_embed, q_b);

  // 3) value / offsets / attention logits
  int gy = (NT + 63) / 64;
  int gy128 = (NT + 127) / 128;
  mgemm128<false,true,false><<<dim3(2, gy128), 256, 0, stream>>>(
      srcb, w_val, b_val, value_b, NT, 256, 256, 256, 256);
  mgemm<true, false,false,false,false><<<dim3(3, gy), 256, 0, stream>>>(
      q_b, w_off, b_off, offbuf, NT, 192, 256, 256, 256, 0, 0);
  mgemm<true, false,false,false,false><<<dim3(2, gy), 256, 0, stream>>>(
      q_b, w_attn, b_attn, awbuf, NT, 96, 256, 256, 256, 0, 0);

  // 4) deformable sampling (softmax fused) -> acc bf16
  deform_sample<<<dim3((NT+255)/256, 8), 256, 0, stream>>>(value_b, offbuf, awbuf, acc_b);

  // 5) out-proj ; x = LN(src + attn) -> xbuf
  mgemm128<true,false,false><<<dim3(2, gy128), 256, 0, stream>>>(
      acc_b, w_out, b_out, s_tmp, NT, 256, 256, 256, 256);
  ln_add<<<(NT+3)/4, 256, 0, stream>>>(srcb, s_tmp, ln1g, ln1b, xbuf, NT);

  // 6) FFN chunked (hbuf = q_b region, 8192x1024 bf16 fits)
  unsigned short* hbuf = q_b;
  for (int c0 = 0; c0 < NT; c0 += 8192) {
    int mc = NT - c0; if (mc > 8192) mc = 8192;
    int gyc = (mc + 127) / 128;
    mgemm128<false,true,true><<<dim3(8, gyc), 256, 0, stream>>>(
        xbuf + (size_t)c0*256, wff1, bff1, hbuf, mc, 1024, 256, 256, 256);
    mgemm128<true,false,false><<<dim3(2, gyc), 256, 0, stream>>>(
        hbuf, wff2, bff2, s_tmp + (size_t)c0*256, mc, 256, 1024, 1024, 1024);
  }

  // 7) x2 = LN(x + y) -> srcb
  ln_add<<<(NT+3)/4, 256, 0, stream>>>(xbuf, s_tmp, ln2g, ln2b, srcb, NT);

  // 8) point bilinear -> pf, fc GEMM -> d_out, gt tail
  point_sample<<<2000, 256, 0, stream>>>(srcb, pc, pf);
  mgemm128<false,false,true><<<dim3(12544/128, (2000+127)/128), 256, 0, stream>>>(
      pf, fcw, fcb, (float*)d_out, 2000, 12544, 256, 256, 256);
  copy_gt<<<8, 256, 0, stream>>>(gt, (float*)d_out + (size_t)2000*12544, 2000);
}

// Round 5
// 722.232 us; speedup vs baseline: 1.3668x; 1.3668x over previous
//
#include <hip/hip_runtime.h>
#include <cstddef>
#include <cstdint>

#define D_MODEL 256
#define LQ 19950
#define NBATCH 2
#define NT (NBATCH*LQ)

typedef short  bf16x8 __attribute__((ext_vector_type(8)));
typedef float  f32x4  __attribute__((ext_vector_type(4)));
typedef unsigned short u16x8 __attribute__((ext_vector_type(8)));

__device__ __forceinline__ unsigned short f2b(float f) {
  unsigned u = __float_as_uint(f);
  u += 0x7fff + ((u >> 16) & 1);          // RNE
  return (unsigned short)(u >> 16);
}
__device__ __forceinline__ float b2f(unsigned short s) {
  return __uint_as_float(((unsigned)s) << 16);
}
__device__ __forceinline__ bf16x8 pack8(float4 a, float4 b) {
  bf16x8 r;
  r[0]=(short)f2b(a.x); r[1]=(short)f2b(a.y); r[2]=(short)f2b(a.z); r[3]=(short)f2b(a.w);
  r[4]=(short)f2b(b.x); r[5]=(short)f2b(b.y); r[6]=(short)f2b(b.z); r[7]=(short)f2b(b.w);
  return r;
}

__device__ __forceinline__ void tok_level(int tok, int& H, int& W, int& loff, int& lvl) {
  if (tok < 15200)      { lvl=0; H=100; W=152; loff=0; }
  else if (tok < 19000) { lvl=1; H=50;  W=76;  loff=15200; }
  else                  { lvl=2; H=25;  W=38;  loff=19000; }
}

// ================= 64x64 bf16-MFMA GEMM =================
// C[M,N] = A[M,K] * B + bias (+relu). A: fp32 or bf16 (ABF).
// B fp32: BKN=false -> B[N,K] (weights, B^T); BKN=true -> B[K,N] (proj feats)
template<bool ABF, bool BKN, bool CBF, bool RELU, bool ROWBIAS>
__global__ __launch_bounds__(256) void mgemm(
    const void* __restrict__ Av, const float* __restrict__ Bv,
    const float* __restrict__ bias, void* __restrict__ Cv,
    int M, int N, int K, int lda, int ldb, long sB, long sC)
{
  __shared__ unsigned short As[64][72];
  __shared__ unsigned short Bs[64][72];
  const int tid = threadIdx.x;
  const float* Bp = Bv + (size_t)blockIdx.z * sB;
  const int n0 = blockIdx.x * 64, m0 = blockIdx.y * 64;
  const int lane = tid & 63;
  const int wave = tid >> 6;
  const int l15 = lane & 15, q = lane >> 4;
  const int m_off = (wave >> 1) * 32, n_off = (wave & 1) * 32;
  f32x4 acc[2][2] = {};

  for (int k0 = 0; k0 < K; k0 += 64) {
    {
      int row = tid >> 2, kc = (tid & 3) * 8;
      int gm = m0 + row;
      bf16x8 v0 = (bf16x8)0, v1 = (bf16x8)0;
      if (gm < M) {
        if constexpr (ABF) {
          const unsigned short* A = (const unsigned short*)Av;
          v0 = *(const bf16x8*)&A[(size_t)gm*lda + k0 + kc];
          v1 = *(const bf16x8*)&A[(size_t)gm*lda + k0 + kc + 32];
        } else {
          const float* A = (const float*)Av;
          const float* p = &A[(size_t)gm*lda + k0 + kc];
          v0 = pack8(*(const float4*)p,      *(const float4*)(p+4));
          v1 = pack8(*(const float4*)(p+32), *(const float4*)(p+36));
        }
      }
      *(bf16x8*)&As[row][kc]    = v0;
      *(bf16x8*)&As[row][kc+32] = v1;
    }
    if constexpr (!BKN) {
      int row = tid >> 2, kc = (tid & 3) * 8;
      int gn = n0 + row;
      bf16x8 v0 = (bf16x8)0, v1 = (bf16x8)0;
      if (gn < N) {
        const float* p = &Bp[(size_t)gn*ldb + k0 + kc];
        v0 = pack8(*(const float4*)p,      *(const float4*)(p+4));
        v1 = pack8(*(const float4*)(p+32), *(const float4*)(p+36));
      }
      *(bf16x8*)&Bs[row][kc]    = v0;
      *(bf16x8*)&Bs[row][kc+32] = v1;
    } else {
      int kr = tid >> 3, nc = (tid & 7) * 8;
      #pragma unroll
      for (int half = 0; half < 2; ++half) {
        int kk = kr + half*32;
        const float* p = &Bp[(size_t)(k0+kk)*ldb + n0 + nc];
        float v[8];
        if (n0 + nc + 7 < N) {
          float2 a0 = *(const float2*)p,     a1 = *(const float2*)(p+2);
          float2 a2 = *(const float2*)(p+4), a3 = *(const float2*)(p+6);
          v[0]=a0.x; v[1]=a0.y; v[2]=a1.x; v[3]=a1.y;
          v[4]=a2.x; v[5]=a2.y; v[6]=a3.x; v[7]=a3.y;
        } else {
          #pragma unroll
          for (int i=0;i<8;++i) v[i] = (n0+nc+i < N) ? p[i] : 0.f;
        }
        #pragma unroll
        for (int i=0;i<8;++i) Bs[nc+i][kk] = f2b(v[i]);
      }
    }
    __syncthreads();
    #pragma unroll
    for (int s = 0; s < 2; ++s) {
      bf16x8 a0 = *(const bf16x8*)&As[m_off      + l15][s*32 + q*8];
      bf16x8 a1 = *(const bf16x8*)&As[m_off + 16 + l15][s*32 + q*8];
      bf16x8 b0 = *(const bf16x8*)&Bs[n_off      + l15][s*32 + q*8];
      bf16x8 b1 = *(const bf16x8*)&Bs[n_off + 16 + l15][s*32 + q*8];
      acc[0][0] = __builtin_amdgcn_mfma_f32_16x16x32_bf16(a0, b0, acc[0][0], 0,0,0);
      acc[0][1] = __builtin_amdgcn_mfma_f32_16x16x32_bf16(a0, b1, acc[0][1], 0,0,0);
      acc[1][0] = __builtin_amdgcn_mfma_f32_16x16x32_bf16(a1, b0, acc[1][0], 0,0,0);
      acc[1][1] = __builtin_amdgcn_mfma_f32_16x16x32_bf16(a1, b1, acc[1][1], 0,0,0);
    }
    __syncthreads();
  }
  float* Cf = (float*)Cv + (size_t)blockIdx.z * sC;
  unsigned short* Cb = (unsigned short*)Cv + (size_t)blockIdx.z * sC;
  #pragma unroll
  for (int r = 0; r < 2; ++r) {
    #pragma unroll
    for (int c = 0; c < 2; ++c) {
      #pragma unroll
      for (int v = 0; v < 4; ++v) {
        int gm = m0 + m_off + r*16 + q*4 + v;
        int gn = n0 + n_off + c*16 + l15;
        if (gm < M && gn < N) {
          float o = acc[r][c][v];
          if (bias) o += ROWBIAS ? bias[gm] : bias[gn];
          if (RELU) o = fmaxf(o, 0.f);
          if constexpr (CBF) Cb[(size_t)gm*N + gn] = f2b(o);
          else               Cf[(size_t)gm*N + gn] = o;
        }
      }
    }
  }
}

// ---------- GN stage 1: partial sums, grid (32 groups, N, 8 chunks) ----------
__global__ __launch_bounds__(256) void gn_partial(
    const float* __restrict__ s, float* __restrict__ partials, int HW)
{
  int g = blockIdx.x, n = blockIdx.y, c = blockIdx.z;
  const float4* base = (const float4*)(s + ((size_t)n*D_MODEL + g*8) * HW);
  int nvec = (8*HW) >> 2;
  float sum = 0.f, sq = 0.f;
  for (int j = c*256 + threadIdx.x; j < nvec; j += 2048) {
    float4 v = base[j];
    sum += v.x+v.y+v.z+v.w;
    sq  += v.x*v.x+v.y*v.y+v.z*v.z+v.w*v.w;
  }
  #pragma unroll
  for (int m=32;m;m>>=1){ sum += __shfl_xor(sum,m,64); sq += __shfl_xor(sq,m,64); }
  __shared__ float s1[4], s2[4];
  int w = threadIdx.x >> 6;
  if ((threadIdx.x & 63) == 0) { s1[w]=sum; s2[w]=sq; }
  __syncthreads();
  if (threadIdx.x == 0) {
    partials[(((size_t)n*32+g)*8 + c)*2]     = s1[0]+s1[1]+s1[2]+s1[3];
    partials[(((size_t)n*32+g)*8 + c)*2 + 1] = s2[0]+s2[1]+s2[2]+s2[3];
  }
}

__global__ __launch_bounds__(64) void gn_finalize(
    const float* __restrict__ partials, float* __restrict__ stats, int HW)
{
  int t = threadIdx.x;
  float S = 0.f, Q = 0.f;
  #pragma unroll
  for (int c = 0; c < 8; ++c) {
    S += partials[((size_t)t*8 + c)*2];
    Q += partials[((size_t)t*8 + c)*2 + 1];
  }
  float inv = 1.f/(float)(8*HW);
  float mu = S*inv;
  float var = Q*inv - mu*mu;
  stats[(size_t)t*2]   = mu;
  stats[(size_t)t*2+1] = rsqrtf(var + 1e-5f);
}

// ---------- apply GN + transpose; emits fp32 src AND bf16 src ----------
__global__ __launch_bounds__(256) void gn_apply(
    const float* __restrict__ s, const float* __restrict__ stats,
    const float* __restrict__ gw, const float* __restrict__ gb,
    float* __restrict__ src, unsigned short* __restrict__ srcbf,
    int HW, int loff)
{
  __shared__ float T[32][33];
  int tx = threadIdx.x & 31, ty = threadIdx.x >> 5;
  int hw0 = blockIdx.x*32, o0 = blockIdx.y*32, n = blockIdx.z;
  const float* base = s + (size_t)n*D_MODEL*HW;
  #pragma unroll
  for (int it=0; it<4; ++it) {
    int ol = ty + it*8;
    int o = o0 + ol;
    int hw = hw0 + tx;
    float v = 0.f;
    if (hw < HW) {
      int grp = o >> 3;
      float mu   = stats[((size_t)n*32+grp)*2];
      float rstd = stats[((size_t)n*32+grp)*2+1];
      v = (base[(size_t)o*HW + hw] - mu)*rstd*gw[o] + gb[o];
    }
    T[ol][tx] = v;
  }
  __syncthreads();
  #pragma unroll
  for (int it=0; it<4; ++it) {
    int tl = ty + it*8;
    int tok = hw0 + tl;
    if (tok < HW) {
      size_t idx = ((size_t)n*LQ + loff + tok)*D_MODEL + o0 + tx;
      float v = T[tx][tl];
      src[idx] = v;
      srcbf[idx] = f2b(v);
    }
  }
}

// ---------- q = bf16(src + sine_pos + level_embed), fast trig ----------
__global__ __launch_bounds__(256) void compute_q(
    const float* __restrict__ src, const float* __restrict__ level_embed,
    unsigned short* __restrict__ q)
{
  int row = blockIdx.x;
  int d = threadIdx.x;
  int tok = row % LQ;
  int H,W,loff,lvl; tok_level(tok,H,W,loff,lvl);
  int hw = tok - loff;
  int i = hw / W, j = hw % W;
  const float TWO_PI = 6.28318530717958647692f;
  float yv = (float)(i+1) / ((float)H + 1e-6f) * TWO_PI;
  float xv = (float)(j+1) / ((float)W + 1e-6f) * TWO_PI;
  int m = (d & 127) >> 1;
  float invt = __expf((float)m * -0.14391156516f);   // 10000^(-m/64)
  float ang = ((d < 128) ? yv : xv) * invt;
  float pe = (d & 1) ? __cosf(ang) : __sinf(ang);
  size_t idx = (size_t)row*D_MODEL + d;
  q[idx] = f2b(src[idx] + pe + level_embed[lvl*D_MODEL + d]);
}

// ---------- deformable sampling (round-3 proven structure) ----------
__global__ __launch_bounds__(256) void deform_sample(
    const unsigned short* __restrict__ value, const float* __restrict__ offb,
    const float* __restrict__ awb, unsigned short* __restrict__ accb)
{
  int idx = blockIdx.x*256 + threadIdx.x;
  if (idx >= NT*8*4) return;
  int quarter = idx & 3;
  int h = (idx >> 2) & 7;
  int row = idx >> 5;
  int tok = row % LQ;
  int n = row / LQ;
  int Ht,Wt,lofft,lvlt; tok_level(tok,Ht,Wt,lofft,lvlt);
  int hw = tok - lofft;
  int ti = hw / Wt, tj = hw % Wt;
  float gxr = ((float)tj + 0.5f) / (float)Wt;
  float gyr = ((float)ti + 0.5f) / (float)Ht;
  const float* offr = offb + (size_t)row*192 + h*24;
  const float* awr  = awb  + (size_t)row*96  + h*12;
  float lg[12];
  float mx = -1e30f;
  #pragma unroll
  for (int i=0;i<12;++i){ lg[i]=awr[i]; mx = fmaxf(mx, lg[i]); }
  float ssum = 0.f;
  #pragma unroll
  for (int i=0;i<12;++i){ lg[i] = __expf(lg[i]-mx); ssum += lg[i]; }
  float sinv = 1.f/ssum;
  float acc[8] = {0.f,0.f,0.f,0.f,0.f,0.f,0.f,0.f};
  const int HH[3]={100,50,25}, WW[3]={152,76,38}, OO[3]={0,15200,19000};
  int chbase = h*32 + quarter*8;
  #pragma unroll
  for (int lvl=0; lvl<3; ++lvl) {
    const int H=HH[lvl], W=WW[lvl], lo=OO[lvl];
    #pragma unroll
    for (int p=0; p<4; ++p) {
      float ox = offr[lvl*8 + p*2];
      float oy = offr[lvl*8 + p*2 + 1];
      float a  = lg[lvl*4 + p] * sinv;
      float x = (gxr + ox / (float)W) * (float)W - 0.5f;
      float y = (gyr + oy / (float)H) * (float)H - 0.5f;
      float x0f = floorf(x), y0f = floorf(y);
      float wx = x - x0f, wy = y - y0f;
      int x0 = (int)x0f, y0 = (int)y0f;
      float tw[4] = { (1.f-wx)*(1.f-wy)*a, wx*(1.f-wy)*a, (1.f-wx)*wy*a, wx*wy*a };
      #pragma unroll
      for (int t=0; t<4; ++t) {
        int xi = x0 + (t & 1), yi = y0 + (t >> 1);
        if (xi >= 0 && xi < W && yi >= 0 && yi < H) {
          const float w = tw[t];
          const unsigned short* vr = value + ((size_t)(n*LQ + lo + yi*W + xi)*D_MODEL + chbase);
          u16x8 v = *(const u16x8*)vr;
          #pragma unroll
          for (int jj=0;jj<8;++jj) acc[jj] += w * b2f(v[jj]);
        }
      }
    }
  }
  unsigned short* o = accb + (size_t)row*D_MODEL + chbase;
  u16x8 ov;
  #pragma unroll
  for (int jj=0;jj<8;++jj) ov[jj] = f2b(acc[jj]);
  *(u16x8*)o = ov;
}

// ---------- out = LN(A+B)*g+b (+ optional bf16 mirror) ----------
template<bool EMITBF>
__global__ __launch_bounds__(256) void ln_add(
    const float* __restrict__ A, const float* __restrict__ B,
    const float* __restrict__ g, const float* __restrict__ b,
    float* __restrict__ out, unsigned short* __restrict__ outbf, int rows)
{
  int wid = (blockIdx.x * 256 + threadIdx.x) >> 6;
  int lane = threadIdx.x & 63;
  if (wid >= rows) return;
  size_t base = (size_t)wid * D_MODEL;
  float4 va = *(const float4*)&A[base + lane*4];
  float4 vb = *(const float4*)&B[base + lane*4];
  float v[4] = {va.x+vb.x, va.y+vb.y, va.z+vb.z, va.w+vb.w};
  float s = v[0]+v[1]+v[2]+v[3];
  #pragma unroll
  for (int m=32; m; m>>=1) s += __shfl_xor(s, m, 64);
  float mu = s * (1.f/256.f);
  float qq = 0.f;
  #pragma unroll
  for (int i=0;i<4;++i){ float d=v[i]-mu; qq += d*d; }
  #pragma unroll
  for (int m=32; m; m>>=1) qq += __shfl_xor(qq, m, 64);
  float rstd = rsqrtf(qq*(1.f/256.f) + 1e-5f);
  float o[4];
  #pragma unroll
  for (int i=0;i<4;++i){
    int d = lane*4+i;
    o[i] = (v[i]-mu)*rstd*g[d] + b[d];
  }
  *(float4*)&out[base + lane*4] = make_float4(o[0],o[1],o[2],o[3]);
  if constexpr (EMITBF) {
    ushort4 ob = { f2b(o[0]), f2b(o[1]), f2b(o[2]), f2b(o[3]) };
    *(ushort4*)&outbf[base + lane*4] = ob;
  }
}

// ---------- point head bilinear ----------
__global__ __launch_bounds__(256) void point_sample(
    const float* __restrict__ x2, const float* __restrict__ pc,
    float* __restrict__ pf)
{
  int pidx = blockIdx.x;
  int n = pidx / 1000;
  float px = pc[(size_t)pidx*2], py = pc[(size_t)pidx*2+1];
  float x = ((2.f*px)*152.f - 1.f)*0.5f;
  float y = ((2.f*py)*100.f - 1.f)*0.5f;
  float x0f=floorf(x), y0f=floorf(y);
  float wx=x-x0f, wy=y-y0f;
  int x0=(int)x0f, y0=(int)y0f;
  int d = threadIdx.x;
  float accv = 0.f;
  #pragma unroll
  for (int t=0;t<4;++t) {
    int xi = x0 + (t&1), yi = y0 + (t>>1);
    float w = ((t&1)?wx:(1.f-wx)) * ((t>>1)?wy:(1.f-wy));
    if (xi>=0 && xi<152 && yi>=0 && yi<100) {
      accv += w * x2[((size_t)(n*LQ + yi*152 + xi))*D_MODEL + d];
    }
  }
  pf[(size_t)pidx*D_MODEL + d] = accv;
}

__global__ void copy_gt(const int* __restrict__ gt, float* __restrict__ out, int nels)
{
  int i = blockIdx.x*256 + threadIdx.x;
  if (i < nels) out[i] = (float)gt[i];
}

extern "C" void kernel_launch(void* const* d_in, const int* in_sizes, int n_in,
                              void* d_out, int out_size, void* d_ws, size_t ws_size,
                              hipStream_t stream)
{
  const float* feat[3]  = {(const float*)d_in[0], (const float*)d_in[1], (const float*)d_in[2]};
  const float* pc       = (const float*)d_in[3];
  const int*   gt       = (const int*)d_in[4];
  const float* projw[3] = {(const float*)d_in[5],  (const float*)d_in[9],  (const float*)d_in[13]};
  const float* projb[3] = {(const float*)d_in[6],  (const float*)d_in[10], (const float*)d_in[14]};
  const float* gng[3]   = {(const float*)d_in[7],  (const float*)d_in[11], (const float*)d_in[15]};
  const float* gnb[3]   = {(const float*)d_in[8],  (const float*)d_in[12], (const float*)d_in[16]};
  const float* level_embed = (const float*)d_in[17];
  const float* w_off  = (const float*)d_in[18];
  const float* b_off  = (const float*)d_in[19];
  const float* w_attn = (const float*)d_in[20];
  const float* b_attn = (const float*)d_in[21];
  const float* w_val  = (const float*)d_in[22];
  const float* b_val  = (const float*)d_in[23];
  const float* w_out  = (const float*)d_in[24];
  const float* b_out  = (const float*)d_in[25];
  const float* ln1g   = (const float*)d_in[26];
  const float* ln1b   = (const float*)d_in[27];
  const float* ln2g   = (const float*)d_in[28];
  const float* ln2b   = (const float*)d_in[29];
  const float* wff1   = (const float*)d_in[30];
  const float* bff1   = (const float*)d_in[31];
  const float* wff2   = (const float*)d_in[32];
  const float* bff2   = (const float*)d_in[33];
  const float* fcw    = (const float*)d_in[34];
  const float* fcb    = (const float*)d_in[35];

  // ---- workspace layout (float units; total 52,349,952 f = 209.4 MB) ----
  float* ws    = (float*)d_ws;
  float* s_tmp = ws;                         // 10,214,400
  float* srcb  = s_tmp + 10214400;           // 10,214,400
  float* offaw = srcb  + 10214400;           // 11,491,200
  unsigned short* value_b = (unsigned short*)(offaw + 11491200); // 10,214,400 us
  unsigned short* acc_b   = value_b + 10214400;                  // 10,214,400 us
  unsigned short* q_b     = acc_b   + 10214400;                  // 10,214,400 us
  unsigned short* src_bf  = q_b     + 10214400;                  // 10,214,400 us
  float* stats    = (float*)(src_bf + 10214400);   // 128
  float* partials = stats + 128;                   // 1024
  float* offbuf = offaw;
  float* awbuf  = offaw + 7660800;
  float* xbuf   = offaw;                           // x fp32 (off/aw dead)
  unsigned short* xb_bf = value_b;                 // x bf16 (value dead)
  float* pf     = (float*)acc_b;                   // pf fp32 (acc dead)

  const int HWs[3]  = {15200, 3800, 950};
  const int Cins[3] = {512, 1024, 2048};
  const int LOFF[3] = {0, 15200, 19000};

  // 1) per-level projection (bf16 MFMA) + GN + transpose (fp32 + bf16 src)
  for (int l = 0; l < 3; ++l) {
    int HW = HWs[l], K = Cins[l];
    mgemm<false,true,false,false,true><<<dim3((HW+63)/64, 4, NBATCH), 256, 0, stream>>>(
        projw[l], feat[l], projb[l], s_tmp, D_MODEL, HW, K, K, HW,
        (long)K*HW, (long)D_MODEL*HW);
    gn_partial<<<dim3(32, NBATCH, 8), 256, 0, stream>>>(s_tmp, partials, HW);
    gn_finalize<<<1, 64, 0, stream>>>(partials, stats, HW);
    gn_apply<<<dim3((HW+31)/32, 8, NBATCH), 256, 0, stream>>>(
        s_tmp, stats, gng[l], gnb[l], srcb, src_bf, HW, LOFF[l]);
  }

  // 2) q = bf16(src + pos)
  compute_q<<<NT, 256, 0, stream>>>(srcb, level_embed, q_b);

  // 3) value / offsets / attention logits (all bf16-A)
  int gy = (NT + 63) / 64;
  mgemm<true,false,true, false,false><<<dim3(4, gy), 256, 0, stream>>>(
      src_bf, w_val, b_val, value_b, NT, 256, 256, 256, 256, 0, 0);
  mgemm<true,false,false,false,false><<<dim3(3, gy), 256, 0, stream>>>(
      q_b, w_off, b_off, offbuf, NT, 192, 256, 256, 256, 0, 0);
  mgemm<true,false,false,false,false><<<dim3(2, gy), 256, 0, stream>>>(
      q_b, w_attn, b_attn, awbuf, NT, 96, 256, 256, 256, 0, 0);

  // 4) deformable sampling (softmax fused) -> acc bf16
  deform_sample<<<(NT*8*4 + 255)/256, 256, 0, stream>>>(value_b, offbuf, awbuf, acc_b);

  // 5) out-proj ; x = LN(src + attn) -> xbuf fp32 + xb_bf bf16
  mgemm<true,false,false,false,false><<<dim3(4, gy), 256, 0, stream>>>(
      acc_b, w_out, b_out, s_tmp, NT, 256, 256, 256, 256, 0, 0);
  ln_add<true><<<(NT+3)/4, 256, 0, stream>>>(srcb, s_tmp, ln1g, ln1b, xbuf, xb_bf, NT);

  // 6) FFN chunked: h = relu(x@W1^T) bf16 (q_b region) ; y -> s_tmp
  unsigned short* hbuf = q_b;
  for (int c0 = 0; c0 < NT; c0 += 8192) {
    int mc = NT - c0; if (mc > 8192) mc = 8192;
    int gyc = (mc + 63) / 64;
    mgemm<true,false,true, true, false><<<dim3(16, gyc), 256, 0, stream>>>(
        xb_bf + (size_t)c0*256, wff1, bff1, hbuf, mc, 1024, 256, 256, 256, 0, 0);
    mgemm<true,false,false,false,false><<<dim3(4, gyc), 256, 0, stream>>>(
        hbuf, wff2, bff2, s_tmp + (size_t)c0*256, mc, 256, 1024, 1024, 1024, 0, 0);
  }

  // 7) x2 = LN(x + y) -> srcb
  ln_add<false><<<(NT+3)/4, 256, 0, stream>>>(xbuf, s_tmp, ln2g, ln2b, srcb, nullptr, NT);

  // 8) point bilinear -> pf, fc GEMM -> d_out, gt tail
  point_sample<<<2000, 256, 0, stream>>>(srcb, pc, pf);
  mgemm<false,false,false,true,false><<<dim3(12544/64, (2000+63)/64), 256, 0, stream>>>(
      pf, fcw, fcb, (float*)d_out, 2000, 12544, 256, 256, 256, 0, 0);
  copy_gt<<<8, 256, 0, stream>>>(gt, (float*)d_out + (size_t)2000*12544, 2000);
}